// Round 1
// baseline (557.004 us; speedup 1.0000x reference)
//
#include <hip/hip_runtime.h>
#include <hip/hip_bf16.h>

// ---------------------------------------------------------------------------
// attn_4329327035017: x[4,2048,1024] fp32 -> qkv GEMM -> causal MHA (16 heads,
// D=64) -> proj GEMM -> out fp32.
// Baseline structure: bf16 MFMA GEMMs (m97-style 128x128 tile), flash attention
// with online softmax (64-row q-blocks, 64-row k/v tiles).
// ---------------------------------------------------------------------------

typedef __attribute__((ext_vector_type(8))) short bf16x8;
typedef __attribute__((ext_vector_type(4))) float f32x4;

#define NEGF -1e30f

__device__ __forceinline__ unsigned short f2bf(float f) {
    unsigned int u = __builtin_bit_cast(unsigned int, f);
    u = (u + 0x7fff + ((u >> 16) & 1)) >> 16;   // RNE
    return (unsigned short)u;
}

__device__ __forceinline__ void async_copy16(const void* gsrc, void* ldsdst) {
    __builtin_amdgcn_global_load_lds(
        (const __attribute__((address_space(1))) unsigned int*)gsrc,
        (__attribute__((address_space(3))) unsigned int*)ldsdst,
        16, 0, 0);
}

// ---------------------------------------------------------------------------
// Conversions
// ---------------------------------------------------------------------------
__global__ void cvt_f32_bf16(const float* __restrict__ in,
                             unsigned short* __restrict__ out, int n) {
    int i = (blockIdx.x * 256 + threadIdx.x) * 4;
    if (i < n) {
        float4 v = *(const float4*)&in[i];
        out[i + 0] = f2bf(v.x);
        out[i + 1] = f2bf(v.y);
        out[i + 2] = f2bf(v.z);
        out[i + 3] = f2bf(v.w);
    }
}

// in: [1024][N] fp32, out: [N][1024] bf16 (B^T layout)
__global__ void transpose_to_bf16(const float* __restrict__ in,
                                  unsigned short* __restrict__ out, int N) {
    size_t i = (size_t)blockIdx.x * 256 + threadIdx.x;
    if (i < (size_t)N * 1024) {
        int k = (int)(i & 1023);
        int n = (int)(i >> 10);
        out[i] = f2bf(in[(size_t)k * N + n]);
    }
}

// ---------------------------------------------------------------------------
// GEMM: C[M][N] = A[M][K] * BT[N][K]^T + bias
// MODE 0: scatter to Q/K/V bf16 [B=4][H=16][T=2048][D=64]
// MODE 1: fp32 out [M][N]
// 128x128 tile, BK=64, 4 waves (2x2), 16x16x32 bf16 MFMA.
// ---------------------------------------------------------------------------
template <int MODE>
__global__ __launch_bounds__(256) void gemm_bf16(
    const unsigned short* __restrict__ A,
    const unsigned short* __restrict__ BT,
    const float* __restrict__ bias,
    float* __restrict__ Cout,
    unsigned short* __restrict__ Qb,
    unsigned short* __restrict__ Kb,
    unsigned short* __restrict__ Vb,
    int M, int N, int K, int tilesM) {
    __shared__ __align__(16) unsigned short As[128 * 64];
    __shared__ __align__(16) unsigned short Bs[128 * 64];

    int bid = blockIdx.x;
    int tm = bid % tilesM, tn = bid / tilesM;
    int m0 = tm * 128, n0 = tn * 128;
    int tid = threadIdx.x;
    int lane = tid & 63, wid = tid >> 6;
    int wr = wid >> 1, wc = wid & 1;
    int l15 = lane & 15, lhi = lane >> 4;

    f32x4 acc[4][4] = {};

    for (int k0 = 0; k0 < K; k0 += 64) {
#pragma unroll
        for (int r = 0; r < 4; r++) {
            int chunk = r * 256 + tid;
            int row = chunk >> 3, cc = chunk & 7;
            async_copy16(&A[(size_t)(m0 + row) * K + k0 + cc * 8],
                         (char*)As + chunk * 16);
        }
#pragma unroll
        for (int r = 0; r < 4; r++) {
            int chunk = r * 256 + tid;
            int row = chunk >> 3, cc = chunk & 7;
            async_copy16(&BT[(size_t)(n0 + row) * K + k0 + cc * 8],
                         (char*)Bs + chunk * 16);
        }
        __syncthreads();
#pragma unroll
        for (int kk = 0; kk < 2; kk++) {
            bf16x8 af[4], bfr[4];
#pragma unroll
            for (int mi = 0; mi < 4; mi++)
                af[mi] = *(const bf16x8*)&As[(wr * 64 + mi * 16 + l15) * 64 +
                                            kk * 32 + lhi * 8];
#pragma unroll
            for (int ni = 0; ni < 4; ni++)
                bfr[ni] = *(const bf16x8*)&Bs[(wc * 64 + ni * 16 + l15) * 64 +
                                              kk * 32 + lhi * 8];
#pragma unroll
            for (int mi = 0; mi < 4; mi++)
#pragma unroll
                for (int ni = 0; ni < 4; ni++)
                    acc[mi][ni] = __builtin_amdgcn_mfma_f32_16x16x32_bf16(
                        af[mi], bfr[ni], acc[mi][ni], 0, 0, 0);
        }
        __syncthreads();
    }

#pragma unroll
    for (int mi = 0; mi < 4; mi++)
#pragma unroll
        for (int ni = 0; ni < 4; ni++)
#pragma unroll
            for (int j = 0; j < 4; j++) {
                int gm = m0 + wr * 64 + mi * 16 + lhi * 4 + j;
                int gn = n0 + wc * 64 + ni * 16 + l15;
                float v = acc[mi][ni][j] + bias[gn];
                if (MODE == 0) {
                    int b = gm >> 11, t = gm & 2047;
                    int sel = gn >> 10, c = gn & 1023;
                    int h = c >> 6, d = c & 63;
                    size_t idx = (((size_t)b * 16 + h) * 2048 + t) * 64 + d;
                    unsigned short bv = f2bf(v);
                    if (sel == 0) Qb[idx] = bv;
                    else if (sel == 1) Kb[idx] = bv;
                    else Vb[idx] = bv;
                } else {
                    Cout[(size_t)gm * N + gn] = v;
                }
            }
}

// ---------------------------------------------------------------------------
// Flash attention, causal. Grid: (B*H)*(T/64) blocks, 256 threads (4 waves).
// Each wave owns 16 q-rows. K/V tiles of 64 staged in LDS.
// ---------------------------------------------------------------------------
__global__ __launch_bounds__(256) void attn_kernel(
    const unsigned short* __restrict__ Qb,
    const unsigned short* __restrict__ Kb,
    const unsigned short* __restrict__ Vb,
    unsigned short* __restrict__ Aout) {
    __shared__ __align__(16) unsigned short Ksm[64 * 64];
    __shared__ __align__(16) unsigned short Vsm[64 * 64];
    __shared__ __align__(16) unsigned short Psm[4 * 16 * 64];

    int bid = blockIdx.x;
    int qb = bid & 31;
    int bh = bid >> 5;           // 0..63
    int b = bh >> 4, h = bh & 15;
    int tid = threadIdx.x, lane = tid & 63, wid = tid >> 6;
    int l15 = lane & 15, lhi = lane >> 4;

    const unsigned short* Qp = Qb + (size_t)bh * 2048 * 64;
    const unsigned short* Kp = Kb + (size_t)bh * 2048 * 64;
    const unsigned short* Vp = Vb + (size_t)bh * 2048 * 64;

    int q0 = qb * 64 + wid * 16;

    bf16x8 aq[2];
#pragma unroll
    for (int kk = 0; kk < 2; kk++)
        aq[kk] = *(const bf16x8*)&Qp[(size_t)(q0 + l15) * 64 + kk * 32 + lhi * 8];

    float m_run[4], l_run[4];
#pragma unroll
    for (int j = 0; j < 4; j++) { m_run[j] = NEGF; l_run[j] = 0.f; }
    f32x4 o_acc[4] = {};

    for (int kt = 0; kt <= qb; kt++) {
#pragma unroll
        for (int r = 0; r < 2; r++) {
            int chunk = r * 256 + tid;
            int row = chunk >> 3, cc = chunk & 7;
            async_copy16(&Kp[(size_t)(kt * 64 + row) * 64 + cc * 8],
                         (char*)Ksm + chunk * 16);
        }
#pragma unroll
        for (int r = 0; r < 2; r++) {
            int chunk = r * 256 + tid;
            int row = chunk >> 3, cc = chunk & 7;
            async_copy16(&Vp[(size_t)(kt * 64 + row) * 64 + cc * 8],
                         (char*)Vsm + chunk * 16);
        }
        __syncthreads();

        f32x4 s[4] = {};
#pragma unroll
        for (int kk = 0; kk < 2; kk++)
#pragma unroll
            for (int nt = 0; nt < 4; nt++) {
                bf16x8 bk = *(const bf16x8*)&Ksm[(nt * 16 + l15) * 64 +
                                                 kk * 32 + lhi * 8];
                s[nt] = __builtin_amdgcn_mfma_f32_16x16x32_bf16(aq[kk], bk,
                                                                s[nt], 0, 0, 0);
            }

        bool diag = (kt == qb);
#pragma unroll
        for (int nt = 0; nt < 4; nt++)
#pragma unroll
            for (int j = 0; j < 4; j++) {
                float v = s[nt][j] * 0.125f;
                if (diag) {
                    int qrow = q0 + lhi * 4 + j;
                    int kcol = kt * 64 + nt * 16 + l15;
                    if (kcol > qrow) v = NEGF;
                }
                s[nt][j] = v;
            }

        float p[4][4], scale_old[4];
#pragma unroll
        for (int j = 0; j < 4; j++) {
            float rmax = fmaxf(fmaxf(s[0][j], s[1][j]), fmaxf(s[2][j], s[3][j]));
#pragma unroll
            for (int off = 1; off < 16; off <<= 1)
                rmax = fmaxf(rmax, __shfl_xor(rmax, off, 64));
            float mnew = fmaxf(m_run[j], rmax);
            float sc = __expf(m_run[j] - mnew);
            float rs = 0.f;
#pragma unroll
            for (int nt = 0; nt < 4; nt++) {
                float e = __expf(s[nt][j] - mnew);
                p[nt][j] = e;
                rs += e;
            }
#pragma unroll
            for (int off = 1; off < 16; off <<= 1)
                rs += __shfl_xor(rs, off, 64);
            l_run[j] = l_run[j] * sc + rs;
            m_run[j] = mnew;
            scale_old[j] = sc;
        }
#pragma unroll
        for (int dt = 0; dt < 4; dt++)
#pragma unroll
            for (int j = 0; j < 4; j++) o_acc[dt][j] *= scale_old[j];

#pragma unroll
        for (int nt = 0; nt < 4; nt++)
#pragma unroll
            for (int j = 0; j < 4; j++)
                Psm[wid * 1024 + (lhi * 4 + j) * 64 + nt * 16 + l15] =
                    f2bf(p[nt][j]);
        __syncthreads();

#pragma unroll
        for (int kk = 0; kk < 2; kk++) {
            bf16x8 ap = *(const bf16x8*)&Psm[wid * 1024 + l15 * 64 + kk * 32 +
                                             lhi * 8];
#pragma unroll
            for (int dt = 0; dt < 4; dt++) {
                bf16x8 bv;
#pragma unroll
                for (int jj = 0; jj < 8; jj++)
                    bv[jj] = (short)Vsm[(kk * 32 + lhi * 8 + jj) * 64 +
                                        dt * 16 + l15];
                o_acc[dt] = __builtin_amdgcn_mfma_f32_16x16x32_bf16(
                    ap, bv, o_acc[dt], 0, 0, 0);
            }
        }
        __syncthreads();
    }

#pragma unroll
    for (int dt = 0; dt < 4; dt++)
#pragma unroll
        for (int j = 0; j < 4; j++) {
            float v = o_acc[dt][j] / l_run[j];
            int t = qb * 64 + wid * 16 + lhi * 4 + j;
            int cc = h * 64 + dt * 16 + l15;
            Aout[((size_t)b * 2048 + t) * 1024 + cc] = f2bf(v);
        }
}

// ---------------------------------------------------------------------------
extern "C" void kernel_launch(void* const* d_in, const int* in_sizes, int n_in,
                              void* d_out, int out_size, void* d_ws,
                              size_t ws_size, hipStream_t stream) {
    const float* x = (const float*)d_in[0];       // [4,2048,1024]
    const float* W_attn = (const float*)d_in[1];  // [1024,3072]
    const float* b_attn = (const float*)d_in[2];  // [3072]
    const float* W_proj = (const float*)d_in[3];  // [1024,1024]
    const float* b_proj = (const float*)d_in[4];  // [1024]
    float* out = (float*)d_out;                   // [4,2048,1024]

    char* ws = (char*)d_ws;
    const size_t MB = 1 << 20;
    unsigned short* xb  = (unsigned short*)(ws + 0);        // 16MB [8192][1024]
    unsigned short* WaT = (unsigned short*)(ws + 16 * MB);  // 6MB  [3072][1024]
    unsigned short* WpT = (unsigned short*)(ws + 22 * MB);  // 2MB  [1024][1024]
    unsigned short* Qb  = (unsigned short*)(ws + 24 * MB);  // 16MB [4][16][2048][64]
    unsigned short* Kb  = (unsigned short*)(ws + 40 * MB);  // 16MB
    unsigned short* Vb  = (unsigned short*)(ws + 56 * MB);  // 16MB
    unsigned short* Att = (unsigned short*)(ws + 72 * MB);  // 16MB [8192][1024]

    const int Mtok = 8192;

    cvt_f32_bf16<<<8192, 256, 0, stream>>>(x, xb, Mtok * 1024);
    transpose_to_bf16<<<12288, 256, 0, stream>>>(W_attn, WaT, 3072);
    transpose_to_bf16<<<4096, 256, 0, stream>>>(W_proj, WpT, 1024);

    // qkv GEMM: M=8192, N=3072, K=1024 -> Q/K/V
    gemm_bf16<0><<<64 * 24, 256, 0, stream>>>(xb, WaT, b_attn, nullptr, Qb, Kb,
                                              Vb, Mtok, 3072, 1024, 64);

    // causal attention: (B*H)=64 x 32 q-blocks
    attn_kernel<<<64 * 32, 256, 0, stream>>>(Qb, Kb, Vb, Att);

    // proj GEMM: M=8192, N=1024, K=1024 -> fp32 out
    gemm_bf16<1><<<64 * 8, 256, 0, stream>>>(Att, WpT, b_proj, out, nullptr,
                                             nullptr, nullptr, Mtok, 1024, 1024,
                                             64);
}

// Round 3
// 446.114 us; speedup vs baseline: 1.2486x; 1.2486x over previous
//
#include <hip/hip_runtime.h>
#include <hip/hip_bf16.h>

// ---------------------------------------------------------------------------
// attn_4329327035017: x[4,2048,1024] fp32 -> qkv GEMM -> causal MHA (16 heads,
// D=64) -> proj GEMM -> out fp32.
// R2 (resubmit; R2 bench was an infra timeout): attention rewrite — V stored
// transposed [bh][d][t]; all attn LDS tiles XOR-swizzled (pre-swizzled global
// source for global_load_lds); QBLK=128; balanced causal qb mapping; setprio
// around MFMA; 2 barriers/tile.
// ---------------------------------------------------------------------------

typedef __attribute__((ext_vector_type(8))) short bf16x8;
typedef __attribute__((ext_vector_type(4))) float f32x4;

#define NEGF -1e30f

__device__ __forceinline__ unsigned short f2bf(float f) {
    unsigned int u = __builtin_bit_cast(unsigned int, f);
    u = (u + 0x7fff + ((u >> 16) & 1)) >> 16;   // RNE
    return (unsigned short)u;
}

__device__ __forceinline__ void async_copy16(const void* gsrc, void* ldsdst) {
    __builtin_amdgcn_global_load_lds(
        (const __attribute__((address_space(1))) unsigned int*)gsrc,
        (__attribute__((address_space(3))) unsigned int*)ldsdst,
        16, 0, 0);
}

// ---------------------------------------------------------------------------
// Conversions
// ---------------------------------------------------------------------------
__global__ void cvt_f32_bf16(const float* __restrict__ in,
                             unsigned short* __restrict__ out, int n) {
    int i = (blockIdx.x * 256 + threadIdx.x) * 4;
    if (i < n) {
        float4 v = *(const float4*)&in[i];
        ushort4 o;
        o.x = f2bf(v.x); o.y = f2bf(v.y); o.z = f2bf(v.z); o.w = f2bf(v.w);
        *(ushort4*)&out[i] = o;
    }
}

// in: [1024][N] fp32, out: [N][1024] bf16 (B^T layout). LDS-tiled transpose.
// grid = (N/32) * (1024/32), block = 256 (8 rows x 32 cols per pass).
__global__ __launch_bounds__(256) void transpose_to_bf16(
    const float* __restrict__ in, unsigned short* __restrict__ out, int N) {
    __shared__ float tile[32][33];
    int ntiles_n = N >> 5;
    int tn = blockIdx.x % ntiles_n;
    int tk = blockIdx.x / ntiles_n;
    int r = threadIdx.x >> 5, c = threadIdx.x & 31;
#pragma unroll
    for (int rr = 0; rr < 32; rr += 8)
        tile[r + rr][c] = in[(size_t)(tk * 32 + r + rr) * N + tn * 32 + c];
    __syncthreads();
#pragma unroll
    for (int rr = 0; rr < 32; rr += 8)
        out[(size_t)(tn * 32 + r + rr) * 1024 + tk * 32 + c] =
            f2bf(tile[c][r + rr]);
}

// ---------------------------------------------------------------------------
// GEMM: C[M][N] = A[M][K] * BT[N][K]^T + bias
// MODE 0: scatter to Q/K bf16 [bh][T][D] and V^T bf16 [bh][D][T]
// MODE 1: fp32 out [M][N]
// 128x128 tile, BK=64, 4 waves (2x2), 16x16x32 bf16 MFMA.
// ---------------------------------------------------------------------------
template <int MODE>
__global__ __launch_bounds__(256) void gemm_bf16(
    const unsigned short* __restrict__ A,
    const unsigned short* __restrict__ BT,
    const float* __restrict__ bias,
    float* __restrict__ Cout,
    unsigned short* __restrict__ Qb,
    unsigned short* __restrict__ Kb,
    unsigned short* __restrict__ VTb,
    int M, int N, int K, int tilesM) {
    __shared__ __align__(16) unsigned short As[128 * 64];
    __shared__ __align__(16) unsigned short Bs[128 * 64];

    int bid = blockIdx.x;
    int tm = bid % tilesM, tn = bid / tilesM;
    int m0 = tm * 128, n0 = tn * 128;
    int tid = threadIdx.x;
    int lane = tid & 63, wid = tid >> 6;
    int wr = wid >> 1, wc = wid & 1;
    int l15 = lane & 15, lhi = lane >> 4;

    f32x4 acc[4][4] = {};

    for (int k0 = 0; k0 < K; k0 += 64) {
#pragma unroll
        for (int r = 0; r < 4; r++) {
            int chunk = r * 256 + tid;
            int row = chunk >> 3, cc = chunk & 7;
            async_copy16(&A[(size_t)(m0 + row) * K + k0 + cc * 8],
                         (char*)As + chunk * 16);
        }
#pragma unroll
        for (int r = 0; r < 4; r++) {
            int chunk = r * 256 + tid;
            int row = chunk >> 3, cc = chunk & 7;
            async_copy16(&BT[(size_t)(n0 + row) * K + k0 + cc * 8],
                         (char*)Bs + chunk * 16);
        }
        __syncthreads();
#pragma unroll
        for (int kk = 0; kk < 2; kk++) {
            bf16x8 af[4], bfr[4];
#pragma unroll
            for (int mi = 0; mi < 4; mi++)
                af[mi] = *(const bf16x8*)&As[(wr * 64 + mi * 16 + l15) * 64 +
                                            kk * 32 + lhi * 8];
#pragma unroll
            for (int ni = 0; ni < 4; ni++)
                bfr[ni] = *(const bf16x8*)&Bs[(wc * 64 + ni * 16 + l15) * 64 +
                                              kk * 32 + lhi * 8];
#pragma unroll
            for (int mi = 0; mi < 4; mi++)
#pragma unroll
                for (int ni = 0; ni < 4; ni++)
                    acc[mi][ni] = __builtin_amdgcn_mfma_f32_16x16x32_bf16(
                        af[mi], bfr[ni], acc[mi][ni], 0, 0, 0);
        }
        __syncthreads();
    }

#pragma unroll
    for (int mi = 0; mi < 4; mi++)
#pragma unroll
        for (int ni = 0; ni < 4; ni++)
#pragma unroll
            for (int j = 0; j < 4; j++) {
                int gm = m0 + wr * 64 + mi * 16 + lhi * 4 + j;
                int gn = n0 + wc * 64 + ni * 16 + l15;
                float v = acc[mi][ni][j] + bias[gn];
                if (MODE == 0) {
                    int b = gm >> 11, t = gm & 2047;
                    int sel = gn >> 10, c = gn & 1023;
                    int h = c >> 6, d = c & 63;
                    int bh = b * 16 + h;
                    unsigned short bv = f2bf(v);
                    if (sel == 0)
                        Qb[((size_t)bh * 2048 + t) * 64 + d] = bv;
                    else if (sel == 1)
                        Kb[((size_t)bh * 2048 + t) * 64 + d] = bv;
                    else
                        VTb[((size_t)bh * 64 + d) * 2048 + t] = bv;
                } else {
                    Cout[(size_t)gm * N + gn] = v;
                }
            }
}

// ---------------------------------------------------------------------------
// Flash attention, causal. QBLK=128, KVBLK=64. Grid: 64 bh x 16 qb = 1024
// blocks, 256 threads (4 waves). Wave w owns 32 q-rows (2 x 16-row frags).
// K and V^T tiles staged via global_load_lds with XOR-swizzle applied on the
// GLOBAL source address (LDS dest stays linear — m173 pattern); all LDS reads
// apply the same swizzle. P is wave-private in LDS (no barrier needed).
// ---------------------------------------------------------------------------
__global__ __launch_bounds__(256) void attn_kernel(
    const unsigned short* __restrict__ Qb,
    const unsigned short* __restrict__ Kb,
    const unsigned short* __restrict__ VTb,
    unsigned short* __restrict__ Aout) {
    __shared__ __align__(16) unsigned short Ksm[64 * 64];   // [kcol][d] swz
    __shared__ __align__(16) unsigned short Vsm[64 * 64];   // [d][kcol] swz
    __shared__ __align__(16) unsigned short Psm[4 * 32 * 64];  // per-wave [q][k] swz

    int bid = blockIdx.x;
    int iq = bid & 15;
    int qb = (iq & 1) ? (15 - (iq >> 1)) : (iq >> 1);  // balanced interleave
    int bh = bid >> 4;
    int b = bh >> 4, h = bh & 15;
    int tid = threadIdx.x, lane = tid & 63, wid = tid >> 6;
    int l15 = lane & 15, lhi = lane >> 4;

    const unsigned short* Qp = Qb + (size_t)bh * 2048 * 64;
    const unsigned short* Kp = Kb + (size_t)bh * 2048 * 64;
    const unsigned short* Vp = VTb + (size_t)bh * 64 * 2048;
    char* Pw = (char*)Psm + wid * 4096;

    int qbase = qb * 128 + wid * 32;

    bf16x8 aq[2][2];
#pragma unroll
    for (int mi = 0; mi < 2; mi++)
#pragma unroll
        for (int kk = 0; kk < 2; kk++)
            aq[mi][kk] = *(const bf16x8*)&Qp[(size_t)(qbase + mi * 16 + l15) * 64 +
                                            kk * 32 + lhi * 8];

    float m_run[2][4], l_run[2][4];
#pragma unroll
    for (int mi = 0; mi < 2; mi++)
#pragma unroll
        for (int j = 0; j < 4; j++) { m_run[mi][j] = NEGF; l_run[mi][j] = 0.f; }
    f32x4 o_acc[2][4] = {};

    int nkt = 2 * qb + 2;
    for (int kt = 0; kt < nkt; kt++) {
        // ---- stage K [64 kcol][64 d] and V^T [64 d][64 t], swizzled source
#pragma unroll
        for (int r = 0; r < 2; r++) {
            int chunk = r * 256 + tid;
            int row = chunk >> 3;
            int el = (((chunk * 16) ^ ((row & 7) << 4)) & 127) >> 1;
            async_copy16(&Kp[(size_t)(kt * 64 + row) * 64 + el],
                         (char*)Ksm + chunk * 16);
        }
#pragma unroll
        for (int r = 0; r < 2; r++) {
            int chunk = r * 256 + tid;
            int row = chunk >> 3;
            int el = (((chunk * 16) ^ ((row & 7) << 4)) & 127) >> 1;
            async_copy16(&Vp[(size_t)row * 2048 + kt * 64 + el],
                         (char*)Vsm + chunk * 16);
        }
        __syncthreads();

        // ---- QK^T
        f32x4 s[2][4] = {};
        __builtin_amdgcn_s_setprio(1);
#pragma unroll
        for (int kk = 0; kk < 2; kk++)
#pragma unroll
            for (int nt = 0; nt < 4; nt++) {
                int row = nt * 16 + l15;
                bf16x8 bk = *(const bf16x8*)((const char*)Ksm +
                    ((row * 128 + kk * 64 + lhi * 16) ^ ((row & 7) << 4)));
#pragma unroll
                for (int mi = 0; mi < 2; mi++)
                    s[mi][nt] = __builtin_amdgcn_mfma_f32_16x16x32_bf16(
                        aq[mi][kk], bk, s[mi][nt], 0, 0, 0);
            }
        __builtin_amdgcn_s_setprio(0);

        // ---- scale + causal mask (only last two tiles touch the diagonal)
        bool diag = (kt >= 2 * qb);
#pragma unroll
        for (int mi = 0; mi < 2; mi++)
#pragma unroll
            for (int nt = 0; nt < 4; nt++)
#pragma unroll
                for (int j = 0; j < 4; j++) {
                    float v = s[mi][nt][j] * 0.125f;
                    if (diag) {
                        int qrow = qbase + mi * 16 + lhi * 4 + j;
                        int kcol = kt * 64 + nt * 16 + l15;
                        if (kcol > qrow) v = NEGF;
                    }
                    s[mi][nt][j] = v;
                }

        // ---- online softmax (reduce over 16 l15 lanes) + P write (wave-local)
#pragma unroll
        for (int mi = 0; mi < 2; mi++)
#pragma unroll
            for (int j = 0; j < 4; j++) {
                float rmax = fmaxf(fmaxf(s[mi][0][j], s[mi][1][j]),
                                   fmaxf(s[mi][2][j], s[mi][3][j]));
#pragma unroll
                for (int off = 1; off < 16; off <<= 1)
                    rmax = fmaxf(rmax, __shfl_xor(rmax, off, 64));
                float mnew = fmaxf(m_run[mi][j], rmax);
                float sc = __expf(m_run[mi][j] - mnew);
                float e0 = __expf(s[mi][0][j] - mnew);
                float e1 = __expf(s[mi][1][j] - mnew);
                float e2 = __expf(s[mi][2][j] - mnew);
                float e3 = __expf(s[mi][3][j] - mnew);
                float rs = (e0 + e1) + (e2 + e3);
#pragma unroll
                for (int off = 1; off < 16; off <<= 1)
                    rs += __shfl_xor(rs, off, 64);
                l_run[mi][j] = l_run[mi][j] * sc + rs;
                m_run[mi][j] = mnew;
#pragma unroll
                for (int dt = 0; dt < 4; dt++) o_acc[mi][dt][j] *= sc;
                int prow = mi * 16 + lhi * 4 + j;
                int pswz = (prow & 7) << 4;
                *(unsigned short*)(Pw + ((prow * 128 + (l15 * 2)) ^ pswz)) = f2bf(e0);
                *(unsigned short*)(Pw + ((prow * 128 + (32 + l15 * 2)) ^ pswz)) = f2bf(e1);
                *(unsigned short*)(Pw + ((prow * 128 + (64 + l15 * 2)) ^ pswz)) = f2bf(e2);
                *(unsigned short*)(Pw + ((prow * 128 + (96 + l15 * 2)) ^ pswz)) = f2bf(e3);
            }

        // ---- PV (P wave-private: no barrier; compiler orders via lgkmcnt)
        __builtin_amdgcn_s_setprio(1);
#pragma unroll
        for (int kk = 0; kk < 2; kk++) {
            bf16x8 ap[2];
#pragma unroll
            for (int mi = 0; mi < 2; mi++) {
                int prow = mi * 16 + l15;
                ap[mi] = *(const bf16x8*)((const char*)Pw +
                    ((prow * 128 + kk * 64 + lhi * 16) ^ ((prow & 7) << 4)));
            }
#pragma unroll
            for (int dt = 0; dt < 4; dt++) {
                int vrow = dt * 16 + l15;
                bf16x8 bv = *(const bf16x8*)((const char*)Vsm +
                    ((vrow * 128 + kk * 64 + lhi * 16) ^ ((vrow & 7) << 4)));
#pragma unroll
                for (int mi = 0; mi < 2; mi++)
                    o_acc[mi][dt] = __builtin_amdgcn_mfma_f32_16x16x32_bf16(
                        ap[mi], bv, o_acc[mi][dt], 0, 0, 0);
            }
        }
        __builtin_amdgcn_s_setprio(0);
        __syncthreads();
    }

    // ---- epilogue
#pragma unroll
    for (int mi = 0; mi < 2; mi++)
#pragma unroll
        for (int dt = 0; dt < 4; dt++)
#pragma unroll
            for (int j = 0; j < 4; j++) {
                float v = o_acc[mi][dt][j] / l_run[mi][j];
                int t = qbase + mi * 16 + lhi * 4 + j;
                int cc = h * 64 + dt * 16 + l15;
                Aout[((size_t)b * 2048 + t) * 1024 + cc] = f2bf(v);
            }
}

// ---------------------------------------------------------------------------
extern "C" void kernel_launch(void* const* d_in, const int* in_sizes, int n_in,
                              void* d_out, int out_size, void* d_ws,
                              size_t ws_size, hipStream_t stream) {
    const float* x = (const float*)d_in[0];       // [4,2048,1024]
    const float* W_attn = (const float*)d_in[1];  // [1024,3072]
    const float* b_attn = (const float*)d_in[2];  // [3072]
    const float* W_proj = (const float*)d_in[3];  // [1024,1024]
    const float* b_proj = (const float*)d_in[4];  // [1024]
    float* out = (float*)d_out;                   // [4,2048,1024]

    char* ws = (char*)d_ws;
    const size_t MB = 1 << 20;
    unsigned short* xb  = (unsigned short*)(ws + 0);        // 16MB [8192][1024]
    unsigned short* WaT = (unsigned short*)(ws + 16 * MB);  // 6MB  [3072][1024]
    unsigned short* WpT = (unsigned short*)(ws + 22 * MB);  // 2MB  [1024][1024]
    unsigned short* Qb  = (unsigned short*)(ws + 24 * MB);  // 16MB [64][2048][64]
    unsigned short* Kb  = (unsigned short*)(ws + 40 * MB);  // 16MB [64][2048][64]
    unsigned short* VTb = (unsigned short*)(ws + 56 * MB);  // 16MB [64][64][2048]
    unsigned short* Att = (unsigned short*)(ws + 72 * MB);  // 16MB [8192][1024]

    const int Mtok = 8192;

    cvt_f32_bf16<<<8192, 256, 0, stream>>>(x, xb, Mtok * 1024);
    transpose_to_bf16<<<96 * 32, 256, 0, stream>>>(W_attn, WaT, 3072);
    transpose_to_bf16<<<32 * 32, 256, 0, stream>>>(W_proj, WpT, 1024);

    // qkv GEMM: M=8192, N=3072, K=1024 -> Q/K/V^T
    gemm_bf16<0><<<64 * 24, 256, 0, stream>>>(xb, WaT, b_attn, nullptr, Qb, Kb,
                                              VTb, Mtok, 3072, 1024, 64);

    // causal attention: 64 bh x 16 q-blocks of 128 rows
    attn_kernel<<<64 * 16, 256, 0, stream>>>(Qb, Kb, VTb, Att);

    // proj GEMM: M=8192, N=1024, K=1024 -> fp32 out
    gemm_bf16<1><<<64 * 8, 256, 0, stream>>>(Att, WpT, b_proj, out, nullptr,
                                             nullptr, nullptr, Mtok, 1024, 1024,
                                             64);
}

// Round 4
// 367.245 us; speedup vs baseline: 1.5167x; 1.2148x over previous
//
#include <hip/hip_runtime.h>
#include <hip/hip_bf16.h>

// ---------------------------------------------------------------------------
// attn_4329327035017: x[4,2048,1024] fp32 -> qkv GEMM -> causal MHA (16 heads,
// D=64) -> proj GEMM -> out fp32.
// R4: swapped QK^T (S^T via mfma(K,Q)) so softmax rows are lane-resident:
// 2 shfls/tile instead of 64, deferred l-reduce, T13 defer-max, exp2-domain.
// K/V double-buffered with stage-before-compute + single barrier per tile.
// V stored row-major in GEMM1 (no scatter); separate LDS transpose kernel.
// ---------------------------------------------------------------------------

typedef __attribute__((ext_vector_type(8))) short bf16x8;
typedef __attribute__((ext_vector_type(4))) float f32x4;

#define NEGF -1e30f

__device__ __forceinline__ unsigned short f2bf(float f) {
    unsigned int u = __builtin_bit_cast(unsigned int, f);
    u = (u + 0x7fff + ((u >> 16) & 1)) >> 16;   // RNE
    return (unsigned short)u;
}

__device__ __forceinline__ void async_copy16(const void* gsrc, void* ldsdst) {
    __builtin_amdgcn_global_load_lds(
        (const __attribute__((address_space(1))) unsigned int*)gsrc,
        (__attribute__((address_space(3))) unsigned int*)ldsdst,
        16, 0, 0);
}

// ---------------------------------------------------------------------------
// Conversions
// ---------------------------------------------------------------------------
__global__ void cvt_f32_bf16(const float* __restrict__ in,
                             unsigned short* __restrict__ out, int n) {
    int i = (blockIdx.x * 256 + threadIdx.x) * 4;
    if (i < n) {
        float4 v = *(const float4*)&in[i];
        ushort4 o;
        o.x = f2bf(v.x); o.y = f2bf(v.y); o.z = f2bf(v.z); o.w = f2bf(v.w);
        *(ushort4*)&out[i] = o;
    }
}

// in: [1024][N] fp32, out: [N][1024] bf16 (B^T layout). LDS-tiled transpose.
__global__ __launch_bounds__(256) void transpose_to_bf16(
    const float* __restrict__ in, unsigned short* __restrict__ out, int N) {
    __shared__ float tile[32][33];
    int ntiles_n = N >> 5;
    int tn = blockIdx.x % ntiles_n;
    int tk = blockIdx.x / ntiles_n;
    int r = threadIdx.x >> 5, c = threadIdx.x & 31;
#pragma unroll
    for (int rr = 0; rr < 32; rr += 8)
        tile[r + rr][c] = in[(size_t)(tk * 32 + r + rr) * N + tn * 32 + c];
    __syncthreads();
#pragma unroll
    for (int rr = 0; rr < 32; rr += 8)
        out[(size_t)(tn * 32 + r + rr) * 1024 + tk * 32 + c] =
            f2bf(tile[c][r + rr]);
}

// V [bh][2048][64] bf16 -> VT [bh][64][2048] bf16. LDS-tiled (64x64 tiles).
// Grid: 64 bh * 32 t-blocks. Stride-65 LDS (scalar LDS ops, ~2-way conflicts);
// global reads/writes stay 16B vectorized & coalesced.
__global__ __launch_bounds__(256) void vtrans(
    const unsigned short* __restrict__ in, unsigned short* __restrict__ out) {
    __shared__ unsigned short t[64][65];
    int bh = blockIdx.x >> 5;
    int t0 = (blockIdx.x & 31) * 64;
    const unsigned short* ip = in + ((size_t)bh * 2048 + t0) * 64;
    unsigned short* op = out + (size_t)bh * 64 * 2048 + t0;
    int tid = threadIdx.x;
#pragma unroll
    for (int i = 0; i < 2; i++) {
        int chunk = i * 256 + tid;
        int row = chunk >> 3, c8 = (chunk & 7) * 8;
        bf16x8 v = *(const bf16x8*)&ip[row * 64 + c8];
#pragma unroll
        for (int jj = 0; jj < 8; jj++) t[row][c8 + jj] = (unsigned short)v[jj];
    }
    __syncthreads();
    int g = tid >> 6, lr = (tid & 63) >> 3, c8 = (tid & 7) * 8;
#pragma unroll
    for (int i = 0; i < 2; i++) {
        int d = i * 32 + g * 8 + lr;
        bf16x8 v;
#pragma unroll
        for (int jj = 0; jj < 8; jj++) v[jj] = (short)t[c8 + jj][d];
        *(bf16x8*)&op[(size_t)d * 2048 + c8] = v;
    }
}

// ---------------------------------------------------------------------------
// GEMM: C[M][N] = A[M][K] * BT[N][K]^T + bias
// MODE 0: scatter to Q/K/V bf16 [bh][T][D] (all row-major now)
// MODE 1: fp32 out [M][N]
// ---------------------------------------------------------------------------
template <int MODE>
__global__ __launch_bounds__(256) void gemm_bf16(
    const unsigned short* __restrict__ A,
    const unsigned short* __restrict__ BT,
    const float* __restrict__ bias,
    float* __restrict__ Cout,
    unsigned short* __restrict__ Qb,
    unsigned short* __restrict__ Kb,
    unsigned short* __restrict__ Vb,
    int M, int N, int K, int tilesM) {
    __shared__ __align__(16) unsigned short As[128 * 64];
    __shared__ __align__(16) unsigned short Bs[128 * 64];

    int bid = blockIdx.x;
    int tm = bid % tilesM, tn = bid / tilesM;
    int m0 = tm * 128, n0 = tn * 128;
    int tid = threadIdx.x;
    int lane = tid & 63, wid = tid >> 6;
    int wr = wid >> 1, wc = wid & 1;
    int l15 = lane & 15, lhi = lane >> 4;

    f32x4 acc[4][4] = {};

    for (int k0 = 0; k0 < K; k0 += 64) {
#pragma unroll
        for (int r = 0; r < 4; r++) {
            int chunk = r * 256 + tid;
            int row = chunk >> 3, cc = chunk & 7;
            async_copy16(&A[(size_t)(m0 + row) * K + k0 + cc * 8],
                         (char*)As + chunk * 16);
        }
#pragma unroll
        for (int r = 0; r < 4; r++) {
            int chunk = r * 256 + tid;
            int row = chunk >> 3, cc = chunk & 7;
            async_copy16(&BT[(size_t)(n0 + row) * K + k0 + cc * 8],
                         (char*)Bs + chunk * 16);
        }
        __syncthreads();
#pragma unroll
        for (int kk = 0; kk < 2; kk++) {
            bf16x8 af[4], bfr[4];
#pragma unroll
            for (int mi = 0; mi < 4; mi++)
                af[mi] = *(const bf16x8*)&As[(wr * 64 + mi * 16 + l15) * 64 +
                                            kk * 32 + lhi * 8];
#pragma unroll
            for (int ni = 0; ni < 4; ni++)
                bfr[ni] = *(const bf16x8*)&Bs[(wc * 64 + ni * 16 + l15) * 64 +
                                              kk * 32 + lhi * 8];
#pragma unroll
            for (int mi = 0; mi < 4; mi++)
#pragma unroll
                for (int ni = 0; ni < 4; ni++)
                    acc[mi][ni] = __builtin_amdgcn_mfma_f32_16x16x32_bf16(
                        af[mi], bfr[ni], acc[mi][ni], 0, 0, 0);
        }
        __syncthreads();
    }

#pragma unroll
    for (int mi = 0; mi < 4; mi++)
#pragma unroll
        for (int ni = 0; ni < 4; ni++)
#pragma unroll
            for (int j = 0; j < 4; j++) {
                int gm = m0 + wr * 64 + mi * 16 + lhi * 4 + j;
                int gn = n0 + wc * 64 + ni * 16 + l15;
                float v = acc[mi][ni][j] + bias[gn];
                if (MODE == 0) {
                    int b = gm >> 11, t = gm & 2047;
                    int sel = gn >> 10, c = gn & 1023;
                    int h = c >> 6, d = c & 63;
                    int bh = b * 16 + h;
                    size_t idx = ((size_t)bh * 2048 + t) * 64 + d;
                    unsigned short bv = f2bf(v);
                    if (sel == 0) Qb[idx] = bv;
                    else if (sel == 1) Kb[idx] = bv;
                    else Vb[idx] = bv;
                } else {
                    Cout[(size_t)gm * N + gn] = v;
                }
            }
}

// ---------------------------------------------------------------------------
// Flash attention, causal. QBLK=128, KVBLK=64, 4 waves. Swapped QK^T:
// s = mfma(K,Q) => S^T, so lane (l15,lhi) holds S[q=qbase+mi*16+l15]
// [k=kt*64+nt*16+lhi*4+reg]. Softmax: in-lane max + 2 shfls; per-lane partial
// l (reduced in epilogue); defer-max (THR=8, log2 domain); P stored as
// ds_write_b64 rows [q][k]. K/V double-buffered, 1 barrier/tile.
// ---------------------------------------------------------------------------
__global__ __launch_bounds__(256) void attn_kernel(
    const unsigned short* __restrict__ Qb,
    const unsigned short* __restrict__ Kb,
    const unsigned short* __restrict__ VTb,
    unsigned short* __restrict__ Aout) {
    __shared__ __align__(16) unsigned short Ksm[2][64 * 64];
    __shared__ __align__(16) unsigned short Vsm[2][64 * 64];
    __shared__ __align__(16) unsigned short Psm[4 * 32 * 64];

    const float CSC = 0.18033688f;  // 0.125 * log2(e)

    int bid = blockIdx.x;
    int iq = bid & 15;
    int qb = (iq & 1) ? (15 - (iq >> 1)) : (iq >> 1);  // balanced interleave
    int bh = bid >> 4;
    int b = bh >> 4, h = bh & 15;
    int tid = threadIdx.x, lane = tid & 63, wid = tid >> 6;
    int l15 = lane & 15, lhi = lane >> 4;

    const unsigned short* Qp = Qb + (size_t)bh * 2048 * 64;
    const unsigned short* Kp = Kb + (size_t)bh * 2048 * 64;
    const unsigned short* Vp = VTb + (size_t)bh * 64 * 2048;
    char* Pw = (char*)Psm + wid * 4096;

    int qbase = qb * 128 + wid * 32;
    int qrow[2] = {qbase + l15, qbase + 16 + l15};

    bf16x8 aq[2][2];
#pragma unroll
    for (int mi = 0; mi < 2; mi++)
#pragma unroll
        for (int kk = 0; kk < 2; kk++)
            aq[mi][kk] = *(const bf16x8*)&Qp[(size_t)(qbase + mi * 16 + l15) * 64 +
                                            kk * 32 + lhi * 8];

    float m_s[2] = {NEGF, NEGF};     // running max, log2-scaled domain
    float l_part[2] = {0.f, 0.f};    // per-lane partial denominator
    f32x4 o_acc[2][4] = {};

    int nkt = 2 * qb + 2;

    // prologue: stage tile 0 into buffer 0
#pragma unroll
    for (int r = 0; r < 2; r++) {
        int chunk = r * 256 + tid;
        int row = chunk >> 3;
        int el = (((chunk * 16) ^ ((row & 7) << 4)) & 127) >> 1;
        async_copy16(&Kp[(size_t)row * 64 + el], (char*)Ksm[0] + chunk * 16);
        async_copy16(&Vp[(size_t)row * 2048 + el], (char*)Vsm[0] + chunk * 16);
    }
    __syncthreads();

    for (int kt = 0; kt < nkt; kt++) {
        int cur = kt & 1;
        // ---- stage next tile into the other buffer (DMA flies under compute)
        if (kt + 1 < nkt) {
#pragma unroll
            for (int r = 0; r < 2; r++) {
                int chunk = r * 256 + tid;
                int row = chunk >> 3;
                int el = (((chunk * 16) ^ ((row & 7) << 4)) & 127) >> 1;
                async_copy16(&Kp[(size_t)((kt + 1) * 64 + row) * 64 + el],
                             (char*)Ksm[cur ^ 1] + chunk * 16);
                async_copy16(&Vp[(size_t)row * 2048 + (kt + 1) * 64 + el],
                             (char*)Vsm[cur ^ 1] + chunk * 16);
            }
        }

        // ---- QK^T, swapped: s[mi][nt] = S^T block (rows=k, cols=q)
        f32x4 s[2][4] = {};
        __builtin_amdgcn_s_setprio(1);
#pragma unroll
        for (int kk = 0; kk < 2; kk++)
#pragma unroll
            for (int nt = 0; nt < 4; nt++) {
                int row = nt * 16 + l15;
                bf16x8 bk = *(const bf16x8*)((const char*)Ksm[cur] +
                    ((row * 128 + kk * 64 + lhi * 16) ^ ((row & 7) << 4)));
#pragma unroll
                for (int mi = 0; mi < 2; mi++)
                    s[mi][nt] = __builtin_amdgcn_mfma_f32_16x16x32_bf16(
                        bk, aq[mi][kk], s[mi][nt], 0, 0, 0);
            }
        __builtin_amdgcn_s_setprio(0);

        // ---- causal mask (uniform branch; only last two tiles hit diagonal)
        if (kt >= 2 * qb) {
#pragma unroll
            for (int mi = 0; mi < 2; mi++)
#pragma unroll
                for (int nt = 0; nt < 4; nt++)
#pragma unroll
                    for (int j = 0; j < 4; j++) {
                        int kcol = kt * 64 + nt * 16 + lhi * 4 + j;
                        if (kcol > qrow[mi]) s[mi][nt][j] = NEGF;
                    }
        }

        // ---- row max: in-lane 16 values + 2 shfls (row is lane-resident)
        float rmax_s[2];
#pragma unroll
        for (int mi = 0; mi < 2; mi++) {
            float r0 = fmaxf(fmaxf(s[mi][0][0], s[mi][0][1]),
                             fmaxf(s[mi][0][2], s[mi][0][3]));
            float r1 = fmaxf(fmaxf(s[mi][1][0], s[mi][1][1]),
                             fmaxf(s[mi][1][2], s[mi][1][3]));
            float r2 = fmaxf(fmaxf(s[mi][2][0], s[mi][2][1]),
                             fmaxf(s[mi][2][2], s[mi][2][3]));
            float r3 = fmaxf(fmaxf(s[mi][3][0], s[mi][3][1]),
                             fmaxf(s[mi][3][2], s[mi][3][3]));
            float rm = fmaxf(fmaxf(r0, r1), fmaxf(r2, r3));
            rm = fmaxf(rm, __shfl_xor(rm, 16, 64));
            rm = fmaxf(rm, __shfl_xor(rm, 32, 64));
            rmax_s[mi] = rm * CSC;
        }

        // ---- defer-max (T13): rescale only when a row's max grew > THR
        bool ok = (rmax_s[0] <= m_s[0] + 8.f) && (rmax_s[1] <= m_s[1] + 8.f);
        if (!__all(ok)) {
#pragma unroll
            for (int mi = 0; mi < 2; mi++) {
                float mn = fmaxf(m_s[mi], rmax_s[mi]);
                float sc = exp2f(m_s[mi] - mn);
                m_s[mi] = mn;
                l_part[mi] *= sc;
#pragma unroll
                for (int dt = 0; dt < 4; dt++)
#pragma unroll
                    for (int j = 0; j < 4; j++) o_acc[mi][dt][j] *= sc;
            }
        }

        // ---- P = exp2(s*CSC - m), accumulate per-lane l, store b64 rows
#pragma unroll
        for (int mi = 0; mi < 2; mi++) {
            float msc = m_s[mi];
            int q = mi * 16 + l15;
            int qx = (q & 7) << 4;
#pragma unroll
            for (int nt = 0; nt < 4; nt++) {
                ushort4 pk;
                float p0 = exp2f(fmaf(s[mi][nt][0], CSC, -msc));
                float p1 = exp2f(fmaf(s[mi][nt][1], CSC, -msc));
                float p2 = exp2f(fmaf(s[mi][nt][2], CSC, -msc));
                float p3 = exp2f(fmaf(s[mi][nt][3], CSC, -msc));
                l_part[mi] += (p0 + p1) + (p2 + p3);
                pk.x = f2bf(p0); pk.y = f2bf(p1);
                pk.z = f2bf(p2); pk.w = f2bf(p3);
                *(ushort4*)(Pw + ((q * 128 + nt * 32 + lhi * 8) ^ qx)) = pk;
            }
        }

        // ---- PV (P wave-private; compiler orders via lgkmcnt)
        __builtin_amdgcn_s_setprio(1);
#pragma unroll
        for (int kk = 0; kk < 2; kk++) {
            bf16x8 ap[2];
#pragma unroll
            for (int mi = 0; mi < 2; mi++) {
                int prow = mi * 16 + l15;
                ap[mi] = *(const bf16x8*)((const char*)Pw +
                    ((prow * 128 + kk * 64 + lhi * 16) ^ ((prow & 7) << 4)));
            }
#pragma unroll
            for (int dt = 0; dt < 4; dt++) {
                int vrow = dt * 16 + l15;
                bf16x8 bv = *(const bf16x8*)((const char*)Vsm[cur] +
                    ((vrow * 128 + kk * 64 + lhi * 16) ^ ((vrow & 7) << 4)));
#pragma unroll
                for (int mi = 0; mi < 2; mi++)
                    o_acc[mi][dt] = __builtin_amdgcn_mfma_f32_16x16x32_bf16(
                        ap[mi], bv, o_acc[mi][dt], 0, 0, 0);
            }
        }
        __builtin_amdgcn_s_setprio(0);
        __syncthreads();   // implicit vmcnt(0): next tile's DMA has landed
    }

    // ---- epilogue: finish l reduction, transport to output layout, store
    float l_red[2];
#pragma unroll
    for (int mi = 0; mi < 2; mi++) {
        float l = l_part[mi];
        l += __shfl_xor(l, 16, 64);
        l += __shfl_xor(l, 32, 64);
        l_red[mi] = l;
    }
#pragma unroll
    for (int mi = 0; mi < 2; mi++)
#pragma unroll
        for (int j = 0; j < 4; j++) {
            float l = __shfl(l_red[mi], lhi * 4 + j, 64);
            float rinv = 1.f / l;
            int t = qbase + mi * 16 + lhi * 4 + j;
#pragma unroll
            for (int dt = 0; dt < 4; dt++) {
                int cc = h * 64 + dt * 16 + l15;
                Aout[((size_t)b * 2048 + t) * 1024 + cc] =
                    f2bf(o_acc[mi][dt][j] * rinv);
            }
        }
}

// ---------------------------------------------------------------------------
extern "C" void kernel_launch(void* const* d_in, const int* in_sizes, int n_in,
                              void* d_out, int out_size, void* d_ws,
                              size_t ws_size, hipStream_t stream) {
    const float* x = (const float*)d_in[0];       // [4,2048,1024]
    const float* W_attn = (const float*)d_in[1];  // [1024,3072]
    const float* b_attn = (const float*)d_in[2];  // [3072]
    const float* W_proj = (const float*)d_in[3];  // [1024,1024]
    const float* b_proj = (const float*)d_in[4];  // [1024]
    float* out = (float*)d_out;                   // [4,2048,1024]

    char* ws = (char*)d_ws;
    const size_t MB = 1 << 20;
    unsigned short* xb  = (unsigned short*)(ws + 0);        // 16MB [8192][1024]
    unsigned short* VTb = (unsigned short*)(ws + 0);        // reuse post-GEMM1
    unsigned short* WaT = (unsigned short*)(ws + 16 * MB);  // 6MB
    unsigned short* WpT = (unsigned short*)(ws + 22 * MB);  // 2MB
    unsigned short* Qb  = (unsigned short*)(ws + 24 * MB);  // 16MB [64][2048][64]
    unsigned short* Kb  = (unsigned short*)(ws + 40 * MB);  // 16MB [64][2048][64]
    unsigned short* Vb  = (unsigned short*)(ws + 56 * MB);  // 16MB [64][2048][64]
    unsigned short* Att = (unsigned short*)(ws + 72 * MB);  // 16MB [8192][1024]

    const int Mtok = 8192;

    cvt_f32_bf16<<<8192, 256, 0, stream>>>(x, xb, Mtok * 1024);
    transpose_to_bf16<<<96 * 32, 256, 0, stream>>>(W_attn, WaT, 3072);
    transpose_to_bf16<<<32 * 32, 256, 0, stream>>>(W_proj, WpT, 1024);

    // qkv GEMM: M=8192, N=3072, K=1024 -> Q/K/V (all row-major)
    gemm_bf16<0><<<64 * 24, 256, 0, stream>>>(xb, WaT, b_attn, nullptr, Qb, Kb,
                                              Vb, Mtok, 3072, 1024, 64);

    // V [bh][t][d] -> VT [bh][d][t]  (xb region is free now)
    vtrans<<<64 * 32, 256, 0, stream>>>(Vb, VTb);

    // causal attention: 64 bh x 16 q-blocks of 128 rows
    attn_kernel<<<64 * 16, 256, 0, stream>>>(Qb, Kb, VTb, Att);

    // proj GEMM: M=8192, N=1024, K=1024 -> fp32 out
    gemm_bf16<1><<<64 * 8, 256, 0, stream>>>(Att, WpT, b_proj, out, nullptr,
                                             nullptr, nullptr, Mtok, 1024, 1024,
                                             64);
}

// Round 7
// 363.155 us; speedup vs baseline: 1.5338x; 1.0113x over previous
//
#include <hip/hip_runtime.h>
#include <hip/hip_bf16.h>

// ---------------------------------------------------------------------------
// attn_4329327035017: x[4,2048,1024] fp32 -> qkv GEMM -> causal MHA (16 heads,
// D=64) -> proj GEMM -> out fp32.
// R7 (= R6 resubmit; R6 bench was an infra timeout): native bf16 casts
// (__float2bfloat16 / __float22bfloat162_rn -> v_cvt_pk_bf16_f32); the
// hand-rolled 4-op RNE conversion was ~40% of the attn VALU pipe. bit_cast ->
// memcpy type-pun (__hip_bfloat162 is not trivially copyable). Structure
// otherwise identical to R4 (swapped QK^T, defer-max, dbuf K/V,
// 1 barrier/tile, XOR-swizzle).
// ---------------------------------------------------------------------------

typedef __attribute__((ext_vector_type(8))) short bf16x8;
typedef __attribute__((ext_vector_type(4))) float f32x4;

#define NEGF -1e30f

__device__ __forceinline__ unsigned short f2bf(float f) {
    __hip_bfloat16 h = __float2bfloat16(f);
    unsigned short u;
    __builtin_memcpy(&u, &h, 2);
    return u;
}
// pack (a,b) -> one dword: a in low 16, b in high 16 (v_cvt_pk_bf16_f32)
__device__ __forceinline__ unsigned int f2bf2(float a, float b) {
    float2 t; t.x = a; t.y = b;
    __hip_bfloat162 r = __float22bfloat162_rn(t);
    unsigned int u;
    __builtin_memcpy(&u, &r, 4);
    return u;
}

__device__ __forceinline__ void async_copy16(const void* gsrc, void* ldsdst) {
    __builtin_amdgcn_global_load_lds(
        (const __attribute__((address_space(1))) unsigned int*)gsrc,
        (__attribute__((address_space(3))) unsigned int*)ldsdst,
        16, 0, 0);
}

// ---------------------------------------------------------------------------
// Conversions
// ---------------------------------------------------------------------------
__global__ void cvt_f32_bf16(const float* __restrict__ in,
                             unsigned short* __restrict__ out, int n) {
    int i = (blockIdx.x * 256 + threadIdx.x) * 4;
    if (i < n) {
        float4 v = *(const float4*)&in[i];
        uint2 o;
        o.x = f2bf2(v.x, v.y);
        o.y = f2bf2(v.z, v.w);
        *(uint2*)&out[i] = o;
    }
}

// in: [1024][N] fp32, out: [N][1024] bf16 (B^T layout). LDS-tiled transpose.
__global__ __launch_bounds__(256) void transpose_to_bf16(
    const float* __restrict__ in, unsigned short* __restrict__ out, int N) {
    __shared__ float tile[32][33];
    int ntiles_n = N >> 5;
    int tn = blockIdx.x % ntiles_n;
    int tk = blockIdx.x / ntiles_n;
    int r = threadIdx.x >> 5, c = threadIdx.x & 31;
#pragma unroll
    for (int rr = 0; rr < 32; rr += 8)
        tile[r + rr][c] = in[(size_t)(tk * 32 + r + rr) * N + tn * 32 + c];
    __syncthreads();
#pragma unroll
    for (int rr = 0; rr < 32; rr += 8)
        out[(size_t)(tn * 32 + r + rr) * 1024 + tk * 32 + c] =
            f2bf(tile[c][r + rr]);
}

// V [bh][2048][64] bf16 -> VT [bh][64][2048] bf16. LDS-tiled (64x64 tiles).
__global__ __launch_bounds__(256) void vtrans(
    const unsigned short* __restrict__ in, unsigned short* __restrict__ out) {
    __shared__ unsigned short t[64][65];
    int bh = blockIdx.x >> 5;
    int t0 = (blockIdx.x & 31) * 64;
    const unsigned short* ip = in + ((size_t)bh * 2048 + t0) * 64;
    unsigned short* op = out + (size_t)bh * 64 * 2048 + t0;
    int tid = threadIdx.x;
#pragma unroll
    for (int i = 0; i < 2; i++) {
        int chunk = i * 256 + tid;
        int row = chunk >> 3, c8 = (chunk & 7) * 8;
        bf16x8 v = *(const bf16x8*)&ip[row * 64 + c8];
#pragma unroll
        for (int jj = 0; jj < 8; jj++) t[row][c8 + jj] = (unsigned short)v[jj];
    }
    __syncthreads();
    int g = tid >> 6, lr = (tid & 63) >> 3, c8 = (tid & 7) * 8;
#pragma unroll
    for (int i = 0; i < 2; i++) {
        int d = i * 32 + g * 8 + lr;
        bf16x8 v;
#pragma unroll
        for (int jj = 0; jj < 8; jj++) v[jj] = (short)t[c8 + jj][d];
        *(bf16x8*)&op[(size_t)d * 2048 + c8] = v;
    }
}

// ---------------------------------------------------------------------------
// GEMM: C[M][N] = A[M][K] * BT[N][K]^T + bias
// MODE 0: scatter to Q/K/V bf16 [bh][T][D] (all row-major)
// MODE 1: fp32 out [M][N]
// ---------------------------------------------------------------------------
template <int MODE>
__global__ __launch_bounds__(256) void gemm_bf16(
    const unsigned short* __restrict__ A,
    const unsigned short* __restrict__ BT,
    const float* __restrict__ bias,
    float* __restrict__ Cout,
    unsigned short* __restrict__ Qb,
    unsigned short* __restrict__ Kb,
    unsigned short* __restrict__ Vb,
    int M, int N, int K, int tilesM) {
    __shared__ __align__(16) unsigned short As[128 * 64];
    __shared__ __align__(16) unsigned short Bs[128 * 64];

    int bid = blockIdx.x;
    int tm = bid % tilesM, tn = bid / tilesM;
    int m0 = tm * 128, n0 = tn * 128;
    int tid = threadIdx.x;
    int lane = tid & 63, wid = tid >> 6;
    int wr = wid >> 1, wc = wid & 1;
    int l15 = lane & 15, lhi = lane >> 4;

    f32x4 acc[4][4] = {};

    for (int k0 = 0; k0 < K; k0 += 64) {
#pragma unroll
        for (int r = 0; r < 4; r++) {
            int chunk = r * 256 + tid;
            int row = chunk >> 3, cc = chunk & 7;
            async_copy16(&A[(size_t)(m0 + row) * K + k0 + cc * 8],
                         (char*)As + chunk * 16);
        }
#pragma unroll
        for (int r = 0; r < 4; r++) {
            int chunk = r * 256 + tid;
            int row = chunk >> 3, cc = chunk & 7;
            async_copy16(&BT[(size_t)(n0 + row) * K + k0 + cc * 8],
                         (char*)Bs + chunk * 16);
        }
        __syncthreads();
#pragma unroll
        for (int kk = 0; kk < 2; kk++) {
            bf16x8 af[4], bfr[4];
#pragma unroll
            for (int mi = 0; mi < 4; mi++)
                af[mi] = *(const bf16x8*)&As[(wr * 64 + mi * 16 + l15) * 64 +
                                            kk * 32 + lhi * 8];
#pragma unroll
            for (int ni = 0; ni < 4; ni++)
                bfr[ni] = *(const bf16x8*)&Bs[(wc * 64 + ni * 16 + l15) * 64 +
                                              kk * 32 + lhi * 8];
#pragma unroll
            for (int mi = 0; mi < 4; mi++)
#pragma unroll
                for (int ni = 0; ni < 4; ni++)
                    acc[mi][ni] = __builtin_amdgcn_mfma_f32_16x16x32_bf16(
                        af[mi], bfr[ni], acc[mi][ni], 0, 0, 0);
        }
        __syncthreads();
    }

#pragma unroll
    for (int mi = 0; mi < 4; mi++)
#pragma unroll
        for (int ni = 0; ni < 4; ni++)
#pragma unroll
            for (int j = 0; j < 4; j++) {
                int gm = m0 + wr * 64 + mi * 16 + lhi * 4 + j;
                int gn = n0 + wc * 64 + ni * 16 + l15;
                float v = acc[mi][ni][j] + bias[gn];
                if (MODE == 0) {
                    int b = gm >> 11, t = gm & 2047;
                    int sel = gn >> 10, c = gn & 1023;
                    int h = c >> 6, d = c & 63;
                    int bh = b * 16 + h;
                    size_t idx = ((size_t)bh * 2048 + t) * 64 + d;
                    unsigned short bv = f2bf(v);
                    if (sel == 0) Qb[idx] = bv;
                    else if (sel == 1) Kb[idx] = bv;
                    else Vb[idx] = bv;
                } else {
                    Cout[(size_t)gm * N + gn] = v;
                }
            }
}

// ---------------------------------------------------------------------------
// Flash attention, causal. QBLK=128, KVBLK=64, 4 waves. Swapped QK^T:
// s = mfma(K,Q) => S^T, lane (l15,lhi) holds S[q=qbase+mi*16+l15]
// [k=kt*64+nt*16+lhi*4+reg]. In-lane row max + 2 shfls; per-lane partial l
// (reduced in epilogue); defer-max (THR=8, log2 domain); P packed with
// cvt_pk and stored as b64 rows. K/V double-buffered, 1 barrier/tile.
// ---------------------------------------------------------------------------
__global__ __launch_bounds__(256) void attn_kernel(
    const unsigned short* __restrict__ Qb,
    const unsigned short* __restrict__ Kb,
    const unsigned short* __restrict__ VTb,
    unsigned short* __restrict__ Aout) {
    __shared__ __align__(16) unsigned short Ksm[2][64 * 64];
    __shared__ __align__(16) unsigned short Vsm[2][64 * 64];
    __shared__ __align__(16) unsigned short Psm[4 * 32 * 64];

    const float CSC = 0.18033688f;  // 0.125 * log2(e)

    int bid = blockIdx.x;
    int iq = bid & 15;
    int qb = (iq & 1) ? (15 - (iq >> 1)) : (iq >> 1);  // balanced interleave
    int bh = bid >> 4;
    int b = bh >> 4, h = bh & 15;
    int tid = threadIdx.x, lane = tid & 63, wid = tid >> 6;
    int l15 = lane & 15, lhi = lane >> 4;

    const unsigned short* Qp = Qb + (size_t)bh * 2048 * 64;
    const unsigned short* Kp = Kb + (size_t)bh * 2048 * 64;
    const unsigned short* Vp = VTb + (size_t)bh * 64 * 2048;
    char* Pw = (char*)Psm + wid * 4096;

    int qbase = qb * 128 + wid * 32;
    int qrow[2] = {qbase + l15, qbase + 16 + l15};

    bf16x8 aq[2][2];
#pragma unroll
    for (int mi = 0; mi < 2; mi++)
#pragma unroll
        for (int kk = 0; kk < 2; kk++)
            aq[mi][kk] = *(const bf16x8*)&Qp[(size_t)(qbase + mi * 16 + l15) * 64 +
                                            kk * 32 + lhi * 8];

    float m_s[2] = {NEGF, NEGF};       // running max, log2-scaled domain
    float2 l_p2[2];                    // per-lane partial denominator (pairs)
    l_p2[0].x = 0.f; l_p2[0].y = 0.f; l_p2[1].x = 0.f; l_p2[1].y = 0.f;
    f32x4 o_acc[2][4] = {};

    int nkt = 2 * qb + 2;

    // prologue: stage tile 0 into buffer 0
#pragma unroll
    for (int r = 0; r < 2; r++) {
        int chunk = r * 256 + tid;
        int row = chunk >> 3;
        int el = (((chunk * 16) ^ ((row & 7) << 4)) & 127) >> 1;
        async_copy16(&Kp[(size_t)row * 64 + el], (char*)Ksm[0] + chunk * 16);
        async_copy16(&Vp[(size_t)row * 2048 + el], (char*)Vsm[0] + chunk * 16);
    }
    __syncthreads();

    for (int kt = 0; kt < nkt; kt++) {
        int cur = kt & 1;
        // ---- stage next tile into the other buffer (DMA flies under compute)
        if (kt + 1 < nkt) {
#pragma unroll
            for (int r = 0; r < 2; r++) {
                int chunk = r * 256 + tid;
                int row = chunk >> 3;
                int el = (((chunk * 16) ^ ((row & 7) << 4)) & 127) >> 1;
                async_copy16(&Kp[(size_t)((kt + 1) * 64 + row) * 64 + el],
                             (char*)Ksm[cur ^ 1] + chunk * 16);
                async_copy16(&Vp[(size_t)row * 2048 + (kt + 1) * 64 + el],
                             (char*)Vsm[cur ^ 1] + chunk * 16);
            }
        }

        // ---- QK^T, swapped: s[mi][nt] = S^T block (rows=k, cols=q)
        f32x4 s[2][4] = {};
        __builtin_amdgcn_s_setprio(1);
#pragma unroll
        for (int kk = 0; kk < 2; kk++)
#pragma unroll
            for (int nt = 0; nt < 4; nt++) {
                int row = nt * 16 + l15;
                bf16x8 bk = *(const bf16x8*)((const char*)Ksm[cur] +
                    ((row * 128 + kk * 64 + lhi * 16) ^ ((row & 7) << 4)));
#pragma unroll
                for (int mi = 0; mi < 2; mi++)
                    s[mi][nt] = __builtin_amdgcn_mfma_f32_16x16x32_bf16(
                        bk, aq[mi][kk], s[mi][nt], 0, 0, 0);
            }
        __builtin_amdgcn_s_setprio(0);

        // ---- causal mask (uniform branch; only last two tiles hit diagonal)
        if (kt >= 2 * qb) {
#pragma unroll
            for (int mi = 0; mi < 2; mi++)
#pragma unroll
                for (int nt = 0; nt < 4; nt++)
#pragma unroll
                    for (int j = 0; j < 4; j++) {
                        int kcol = kt * 64 + nt * 16 + lhi * 4 + j;
                        if (kcol > qrow[mi]) s[mi][nt][j] = NEGF;
                    }
        }

        // ---- row max: in-lane 16 values + 2 shfls (row is lane-resident)
        float rmax_s[2];
#pragma unroll
        for (int mi = 0; mi < 2; mi++) {
            float r0 = fmaxf(fmaxf(s[mi][0][0], s[mi][0][1]),
                             fmaxf(s[mi][0][2], s[mi][0][3]));
            float r1 = fmaxf(fmaxf(s[mi][1][0], s[mi][1][1]),
                             fmaxf(s[mi][1][2], s[mi][1][3]));
            float r2 = fmaxf(fmaxf(s[mi][2][0], s[mi][2][1]),
                             fmaxf(s[mi][2][2], s[mi][2][3]));
            float r3 = fmaxf(fmaxf(s[mi][3][0], s[mi][3][1]),
                             fmaxf(s[mi][3][2], s[mi][3][3]));
            float rm = fmaxf(fmaxf(r0, r1), fmaxf(r2, r3));
            rm = fmaxf(rm, __shfl_xor(rm, 16, 64));
            rm = fmaxf(rm, __shfl_xor(rm, 32, 64));
            rmax_s[mi] = rm * CSC;
        }

        // ---- defer-max (T13): rescale only when a row's max grew > THR
        bool ok = (rmax_s[0] <= m_s[0] + 8.f) && (rmax_s[1] <= m_s[1] + 8.f);
        if (!__all(ok)) {
#pragma unroll
            for (int mi = 0; mi < 2; mi++) {
                float mn = fmaxf(m_s[mi], rmax_s[mi]);
                float sc = exp2f(m_s[mi] - mn);
                m_s[mi] = mn;
                l_p2[mi].x *= sc;
                l_p2[mi].y *= sc;
#pragma unroll
                for (int dt = 0; dt < 4; dt++)
#pragma unroll
                    for (int j = 0; j < 4; j++) o_acc[mi][dt][j] *= sc;
            }
        }

        // ---- P = exp2(s*CSC - m), per-lane l (float2), cvt_pk + b64 store
#pragma unroll
        for (int mi = 0; mi < 2; mi++) {
            float msc = m_s[mi];
            int q = mi * 16 + l15;
            int qx = (q & 7) << 4;
#pragma unroll
            for (int nt = 0; nt < 4; nt++) {
                float p0 = exp2f(fmaf(s[mi][nt][0], CSC, -msc));
                float p1 = exp2f(fmaf(s[mi][nt][1], CSC, -msc));
                float p2 = exp2f(fmaf(s[mi][nt][2], CSC, -msc));
                float p3 = exp2f(fmaf(s[mi][nt][3], CSC, -msc));
                l_p2[mi].x += p0 + p2;
                l_p2[mi].y += p1 + p3;
                uint2 pk;
                pk.x = f2bf2(p0, p1);
                pk.y = f2bf2(p2, p3);
                *(uint2*)(Pw + ((q * 128 + nt * 32 + lhi * 8) ^ qx)) = pk;
            }
        }

        // ---- PV (P wave-private; compiler orders via lgkmcnt)
        __builtin_amdgcn_s_setprio(1);
#pragma unroll
        for (int kk = 0; kk < 2; kk++) {
            bf16x8 ap[2];
#pragma unroll
            for (int mi = 0; mi < 2; mi++) {
                int prow = mi * 16 + l15;
                ap[mi] = *(const bf16x8*)((const char*)Pw +
                    ((prow * 128 + kk * 64 + lhi * 16) ^ ((prow & 7) << 4)));
            }
#pragma unroll
            for (int dt = 0; dt < 4; dt++) {
                int vrow = dt * 16 + l15;
                bf16x8 bv = *(const bf16x8*)((const char*)Vsm[cur] +
                    ((vrow * 128 + kk * 64 + lhi * 16) ^ ((vrow & 7) << 4)));
#pragma unroll
                for (int mi = 0; mi < 2; mi++)
                    o_acc[mi][dt] = __builtin_amdgcn_mfma_f32_16x16x32_bf16(
                        ap[mi], bv, o_acc[mi][dt], 0, 0, 0);
            }
        }
        __builtin_amdgcn_s_setprio(0);
        __syncthreads();   // implicit vmcnt(0): next tile's DMA has landed
    }

    // ---- epilogue: finish l reduction, transport to output layout, store
    float l_red[2];
#pragma unroll
    for (int mi = 0; mi < 2; mi++) {
        float l = l_p2[mi].x + l_p2[mi].y;
        l += __shfl_xor(l, 16, 64);
        l += __shfl_xor(l, 32, 64);
        l_red[mi] = l;
    }
#pragma unroll
    for (int mi = 0; mi < 2; mi++)
#pragma unroll
        for (int j = 0; j < 4; j++) {
            float l = __shfl(l_red[mi], lhi * 4 + j, 64);
            float rinv = 1.f / l;
            int t = qbase + mi * 16 + lhi * 4 + j;
#pragma unroll
            for (int dt = 0; dt < 4; dt++) {
                int cc = h * 64 + dt * 16 + l15;
                Aout[((size_t)b * 2048 + t) * 1024 + cc] =
                    f2bf(o_acc[mi][dt][j] * rinv);
            }
        }
}

// ---------------------------------------------------------------------------
extern "C" void kernel_launch(void* const* d_in, const int* in_sizes, int n_in,
                              void* d_out, int out_size, void* d_ws,
                              size_t ws_size, hipStream_t stream) {
    const float* x = (const float*)d_in[0];       // [4,2048,1024]
    const float* W_attn = (const float*)d_in[1];  // [1024,3072]
    const float* b_attn = (const float*)d_in[2];  // [3072]
    const float* W_proj = (const float*)d_in[3];  // [1024,1024]
    const float* b_proj = (const float*)d_in[4];  // [1024]
    float* out = (float*)d_out;                   // [4,2048,1024]

    char* ws = (char*)d_ws;
    const size_t MB = 1 << 20;
    unsigned short* xb  = (unsigned short*)(ws + 0);        // 16MB [8192][1024]
    unsigned short* VTb = (unsigned short*)(ws + 0);        // reuse post-GEMM1
    unsigned short* WaT = (unsigned short*)(ws + 16 * MB);  // 6MB
    unsigned short* WpT = (unsigned short*)(ws + 22 * MB);  // 2MB
    unsigned short* Qb  = (unsigned short*)(ws + 24 * MB);  // 16MB [64][2048][64]
    unsigned short* Kb  = (unsigned short*)(ws + 40 * MB);  // 16MB [64][2048][64]
    unsigned short* Vb  = (unsigned short*)(ws + 56 * MB);  // 16MB [64][2048][64]
    unsigned short* Att = (unsigned short*)(ws + 72 * MB);  // 16MB [8192][1024]

    const int Mtok = 8192;

    cvt_f32_bf16<<<8192, 256, 0, stream>>>(x, xb, Mtok * 1024);
    transpose_to_bf16<<<96 * 32, 256, 0, stream>>>(W_attn, WaT, 3072);
    transpose_to_bf16<<<32 * 32, 256, 0, stream>>>(W_proj, WpT, 1024);

    // qkv GEMM: M=8192, N=3072, K=1024 -> Q/K/V (all row-major)
    gemm_bf16<0><<<64 * 24, 256, 0, stream>>>(xb, WaT, b_attn, nullptr, Qb, Kb,
                                              Vb, Mtok, 3072, 1024, 64);

    // V [bh][t][d] -> VT [bh][d][t]  (xb region is free now)
    vtrans<<<64 * 32, 256, 0, stream>>>(Vb, VTb);

    // causal attention: 64 bh x 16 q-blocks of 128 rows
    attn_kernel<<<64 * 16, 256, 0, stream>>>(Qb, Kb, VTb, Att);

    // proj GEMM: M=8192, N=1024, K=1024 -> fp32 out
    gemm_bf16<1><<<64 * 8, 256, 0, stream>>>(Att, WpT, b_proj, out, nullptr,
                                             nullptr, nullptr, Mtok, 1024, 1024,
                                             64);
}

// Round 8
// 311.008 us; speedup vs baseline: 1.7910x; 1.1677x over previous
//
#include <hip/hip_runtime.h>
#include <hip/hip_bf16.h>

// ---------------------------------------------------------------------------
// attn_4329327035017: x[4,2048,1024] fp32 -> qkv GEMM -> causal MHA (16 heads,
// D=64) -> proj GEMM -> out fp32.
// R8: persistent work-queue attention. R7 showed OccupancyPercent 11% with
// neither pipe saturated (VALU 38 / MFMA 9 / HBM 9%): latency-bound, too few
// resident waves + causal tail imbalance (block work varies 2..32 tiles).
// Grid = 768 persistent blocks (3/CU LDS-bound); units (bh,qb) pulled from a
// device atomic counter, longest-first (qb=15 down to 0). Counter in dead Vb
// region, zeroed via hipMemsetAsync before the attn launch (graph-safe).
// Attn tile structure unchanged from R7 (swapped QK^T, defer-max, dbuf K/V,
// 1 barrier/tile, XOR-swizzle, cvt_pk P-pack).
// ---------------------------------------------------------------------------

typedef __attribute__((ext_vector_type(8))) short bf16x8;
typedef __attribute__((ext_vector_type(4))) float f32x4;

#define NEGF -1e30f

__device__ __forceinline__ unsigned short f2bf(float f) {
    __hip_bfloat16 h = __float2bfloat16(f);
    unsigned short u;
    __builtin_memcpy(&u, &h, 2);
    return u;
}
// pack (a,b) -> one dword: a in low 16, b in high 16 (v_cvt_pk_bf16_f32)
__device__ __forceinline__ unsigned int f2bf2(float a, float b) {
    float2 t; t.x = a; t.y = b;
    __hip_bfloat162 r = __float22bfloat162_rn(t);
    unsigned int u;
    __builtin_memcpy(&u, &r, 4);
    return u;
}

__device__ __forceinline__ void async_copy16(const void* gsrc, void* ldsdst) {
    __builtin_amdgcn_global_load_lds(
        (const __attribute__((address_space(1))) unsigned int*)gsrc,
        (__attribute__((address_space(3))) unsigned int*)ldsdst,
        16, 0, 0);
}

// ---------------------------------------------------------------------------
// Conversions
// ---------------------------------------------------------------------------
__global__ void cvt_f32_bf16(const float* __restrict__ in,
                             unsigned short* __restrict__ out, int n) {
    int i = (blockIdx.x * 256 + threadIdx.x) * 4;
    if (i < n) {
        float4 v = *(const float4*)&in[i];
        uint2 o;
        o.x = f2bf2(v.x, v.y);
        o.y = f2bf2(v.z, v.w);
        *(uint2*)&out[i] = o;
    }
}

// in: [1024][N] fp32, out: [N][1024] bf16 (B^T layout). LDS-tiled transpose.
__global__ __launch_bounds__(256) void transpose_to_bf16(
    const float* __restrict__ in, unsigned short* __restrict__ out, int N) {
    __shared__ float tile[32][33];
    int ntiles_n = N >> 5;
    int tn = blockIdx.x % ntiles_n;
    int tk = blockIdx.x / ntiles_n;
    int r = threadIdx.x >> 5, c = threadIdx.x & 31;
#pragma unroll
    for (int rr = 0; rr < 32; rr += 8)
        tile[r + rr][c] = in[(size_t)(tk * 32 + r + rr) * N + tn * 32 + c];
    __syncthreads();
#pragma unroll
    for (int rr = 0; rr < 32; rr += 8)
        out[(size_t)(tn * 32 + r + rr) * 1024 + tk * 32 + c] =
            f2bf(tile[c][r + rr]);
}

// V [bh][2048][64] bf16 -> VT [bh][64][2048] bf16. LDS-tiled (64x64 tiles).
__global__ __launch_bounds__(256) void vtrans(
    const unsigned short* __restrict__ in, unsigned short* __restrict__ out) {
    __shared__ unsigned short t[64][65];
    int bh = blockIdx.x >> 5;
    int t0 = (blockIdx.x & 31) * 64;
    const unsigned short* ip = in + ((size_t)bh * 2048 + t0) * 64;
    unsigned short* op = out + (size_t)bh * 64 * 2048 + t0;
    int tid = threadIdx.x;
#pragma unroll
    for (int i = 0; i < 2; i++) {
        int chunk = i * 256 + tid;
        int row = chunk >> 3, c8 = (chunk & 7) * 8;
        bf16x8 v = *(const bf16x8*)&ip[row * 64 + c8];
#pragma unroll
        for (int jj = 0; jj < 8; jj++) t[row][c8 + jj] = (unsigned short)v[jj];
    }
    __syncthreads();
    int g = tid >> 6, lr = (tid & 63) >> 3, c8 = (tid & 7) * 8;
#pragma unroll
    for (int i = 0; i < 2; i++) {
        int d = i * 32 + g * 8 + lr;
        bf16x8 v;
#pragma unroll
        for (int jj = 0; jj < 8; jj++) v[jj] = (short)t[c8 + jj][d];
        *(bf16x8*)&op[(size_t)d * 2048 + c8] = v;
    }
}

// ---------------------------------------------------------------------------
// GEMM: C[M][N] = A[M][K] * BT[N][K]^T + bias
// MODE 0: scatter to Q/K/V bf16 [bh][T][D] (all row-major)
// MODE 1: fp32 out [M][N]
// ---------------------------------------------------------------------------
template <int MODE>
__global__ __launch_bounds__(256) void gemm_bf16(
    const unsigned short* __restrict__ A,
    const unsigned short* __restrict__ BT,
    const float* __restrict__ bias,
    float* __restrict__ Cout,
    unsigned short* __restrict__ Qb,
    unsigned short* __restrict__ Kb,
    unsigned short* __restrict__ Vb,
    int M, int N, int K, int tilesM) {
    __shared__ __align__(16) unsigned short As[128 * 64];
    __shared__ __align__(16) unsigned short Bs[128 * 64];

    int bid = blockIdx.x;
    int tm = bid % tilesM, tn = bid / tilesM;
    int m0 = tm * 128, n0 = tn * 128;
    int tid = threadIdx.x;
    int lane = tid & 63, wid = tid >> 6;
    int wr = wid >> 1, wc = wid & 1;
    int l15 = lane & 15, lhi = lane >> 4;

    f32x4 acc[4][4] = {};

    for (int k0 = 0; k0 < K; k0 += 64) {
#pragma unroll
        for (int r = 0; r < 4; r++) {
            int chunk = r * 256 + tid;
            int row = chunk >> 3, cc = chunk & 7;
            async_copy16(&A[(size_t)(m0 + row) * K + k0 + cc * 8],
                         (char*)As + chunk * 16);
        }
#pragma unroll
        for (int r = 0; r < 4; r++) {
            int chunk = r * 256 + tid;
            int row = chunk >> 3, cc = chunk & 7;
            async_copy16(&BT[(size_t)(n0 + row) * K + k0 + cc * 8],
                         (char*)Bs + chunk * 16);
        }
        __syncthreads();
#pragma unroll
        for (int kk = 0; kk < 2; kk++) {
            bf16x8 af[4], bfr[4];
#pragma unroll
            for (int mi = 0; mi < 4; mi++)
                af[mi] = *(const bf16x8*)&As[(wr * 64 + mi * 16 + l15) * 64 +
                                            kk * 32 + lhi * 8];
#pragma unroll
            for (int ni = 0; ni < 4; ni++)
                bfr[ni] = *(const bf16x8*)&Bs[(wc * 64 + ni * 16 + l15) * 64 +
                                              kk * 32 + lhi * 8];
#pragma unroll
            for (int mi = 0; mi < 4; mi++)
#pragma unroll
                for (int ni = 0; ni < 4; ni++)
                    acc[mi][ni] = __builtin_amdgcn_mfma_f32_16x16x32_bf16(
                        af[mi], bfr[ni], acc[mi][ni], 0, 0, 0);
        }
        __syncthreads();
    }

#pragma unroll
    for (int mi = 0; mi < 4; mi++)
#pragma unroll
        for (int ni = 0; ni < 4; ni++)
#pragma unroll
            for (int j = 0; j < 4; j++) {
                int gm = m0 + wr * 64 + mi * 16 + lhi * 4 + j;
                int gn = n0 + wc * 64 + ni * 16 + l15;
                float v = acc[mi][ni][j] + bias[gn];
                if (MODE == 0) {
                    int b = gm >> 11, t = gm & 2047;
                    int sel = gn >> 10, c = gn & 1023;
                    int h = c >> 6, d = c & 63;
                    int bh = b * 16 + h;
                    size_t idx = ((size_t)bh * 2048 + t) * 64 + d;
                    unsigned short bv = f2bf(v);
                    if (sel == 0) Qb[idx] = bv;
                    else if (sel == 1) Kb[idx] = bv;
                    else Vb[idx] = bv;
                } else {
                    Cout[(size_t)gm * N + gn] = v;
                }
            }
}

// ---------------------------------------------------------------------------
// Flash attention, causal, persistent. 768 blocks x 4 waves pull (bh,qb)
// units from a global counter, longest-first (qb=15..0). Per unit: QBLK=128,
// KVBLK=64; swapped QK^T (S^T via mfma(K,Q)), lane-resident softmax rows,
// defer-max, per-lane partial l, cvt_pk P-pack, dbuf K/V, 1 barrier/tile.
// ---------------------------------------------------------------------------
__global__ __launch_bounds__(256) void attn_kernel(
    const unsigned short* __restrict__ Qb,
    const unsigned short* __restrict__ Kb,
    const unsigned short* __restrict__ VTb,
    unsigned short* __restrict__ Aout,
    unsigned int* __restrict__ ctr) {
    __shared__ __align__(16) unsigned short Ksm[2][64 * 64];
    __shared__ __align__(16) unsigned short Vsm[2][64 * 64];
    __shared__ __align__(16) unsigned short Psm[4 * 32 * 64];
    __shared__ unsigned int s_unit;

    const float CSC = 0.18033688f;  // 0.125 * log2(e)

    int tid = threadIdx.x, lane = tid & 63, wid = tid >> 6;
    int l15 = lane & 15, lhi = lane >> 4;
    char* Pw = (char*)Psm + wid * 4096;

    for (;;) {
        __syncthreads();                   // all threads done with prev s_unit
        if (tid == 0) s_unit = atomicAdd(ctr, 1u);
        __syncthreads();
        unsigned int u = s_unit;
        if (u >= 1024u) break;             // uniform exit

        int qb = 15 - (int)(u >> 6);       // longest work first
        int bh = (int)(u & 63u);
        int b = bh >> 4, h = bh & 15;

        const unsigned short* Qp = Qb + (size_t)bh * 2048 * 64;
        const unsigned short* Kp = Kb + (size_t)bh * 2048 * 64;
        const unsigned short* Vp = VTb + (size_t)bh * 64 * 2048;

        int qbase = qb * 128 + wid * 32;
        int qrow[2] = {qbase + l15, qbase + 16 + l15};

        bf16x8 aq[2][2];
#pragma unroll
        for (int mi = 0; mi < 2; mi++)
#pragma unroll
            for (int kk = 0; kk < 2; kk++)
                aq[mi][kk] = *(const bf16x8*)&Qp[(size_t)(qbase + mi * 16 + l15) *
                                                    64 + kk * 32 + lhi * 8];

        float m_s[2] = {NEGF, NEGF};     // running max, log2-scaled domain
        float2 l_p2[2];
        l_p2[0].x = 0.f; l_p2[0].y = 0.f; l_p2[1].x = 0.f; l_p2[1].y = 0.f;
        f32x4 o_acc[2][4] = {};

        int nkt = 2 * qb + 2;

        // prologue: stage tile 0 into buffer 0
#pragma unroll
        for (int r = 0; r < 2; r++) {
            int chunk = r * 256 + tid;
            int row = chunk >> 3;
            int el = (((chunk * 16) ^ ((row & 7) << 4)) & 127) >> 1;
            async_copy16(&Kp[(size_t)row * 64 + el], (char*)Ksm[0] + chunk * 16);
            async_copy16(&Vp[(size_t)row * 2048 + el], (char*)Vsm[0] + chunk * 16);
        }
        __syncthreads();

        for (int kt = 0; kt < nkt; kt++) {
            int cur = kt & 1;
            // ---- stage next tile into the other buffer
            if (kt + 1 < nkt) {
#pragma unroll
                for (int r = 0; r < 2; r++) {
                    int chunk = r * 256 + tid;
                    int row = chunk >> 3;
                    int el = (((chunk * 16) ^ ((row & 7) << 4)) & 127) >> 1;
                    async_copy16(&Kp[(size_t)((kt + 1) * 64 + row) * 64 + el],
                                 (char*)Ksm[cur ^ 1] + chunk * 16);
                    async_copy16(&Vp[(size_t)row * 2048 + (kt + 1) * 64 + el],
                                 (char*)Vsm[cur ^ 1] + chunk * 16);
                }
            }

            // ---- QK^T, swapped: s[mi][nt] = S^T block (rows=k, cols=q)
            f32x4 s[2][4] = {};
            __builtin_amdgcn_s_setprio(1);
#pragma unroll
            for (int kk = 0; kk < 2; kk++)
#pragma unroll
                for (int nt = 0; nt < 4; nt++) {
                    int row = nt * 16 + l15;
                    bf16x8 bk = *(const bf16x8*)((const char*)Ksm[cur] +
                        ((row * 128 + kk * 64 + lhi * 16) ^ ((row & 7) << 4)));
#pragma unroll
                    for (int mi = 0; mi < 2; mi++)
                        s[mi][nt] = __builtin_amdgcn_mfma_f32_16x16x32_bf16(
                            bk, aq[mi][kk], s[mi][nt], 0, 0, 0);
                }
            __builtin_amdgcn_s_setprio(0);

            // ---- causal mask (only last two tiles hit the diagonal)
            if (kt >= 2 * qb) {
#pragma unroll
                for (int mi = 0; mi < 2; mi++)
#pragma unroll
                    for (int nt = 0; nt < 4; nt++)
#pragma unroll
                        for (int j = 0; j < 4; j++) {
                            int kcol = kt * 64 + nt * 16 + lhi * 4 + j;
                            if (kcol > qrow[mi]) s[mi][nt][j] = NEGF;
                        }
            }

            // ---- row max: in-lane 16 values + 2 shfls
            float rmax_s[2];
#pragma unroll
            for (int mi = 0; mi < 2; mi++) {
                float r0 = fmaxf(fmaxf(s[mi][0][0], s[mi][0][1]),
                                 fmaxf(s[mi][0][2], s[mi][0][3]));
                float r1 = fmaxf(fmaxf(s[mi][1][0], s[mi][1][1]),
                                 fmaxf(s[mi][1][2], s[mi][1][3]));
                float r2 = fmaxf(fmaxf(s[mi][2][0], s[mi][2][1]),
                                 fmaxf(s[mi][2][2], s[mi][2][3]));
                float r3 = fmaxf(fmaxf(s[mi][3][0], s[mi][3][1]),
                                 fmaxf(s[mi][3][2], s[mi][3][3]));
                float rm = fmaxf(fmaxf(r0, r1), fmaxf(r2, r3));
                rm = fmaxf(rm, __shfl_xor(rm, 16, 64));
                rm = fmaxf(rm, __shfl_xor(rm, 32, 64));
                rmax_s[mi] = rm * CSC;
            }

            // ---- defer-max (T13)
            bool ok = (rmax_s[0] <= m_s[0] + 8.f) && (rmax_s[1] <= m_s[1] + 8.f);
            if (!__all(ok)) {
#pragma unroll
                for (int mi = 0; mi < 2; mi++) {
                    float mn = fmaxf(m_s[mi], rmax_s[mi]);
                    float sc = exp2f(m_s[mi] - mn);
                    m_s[mi] = mn;
                    l_p2[mi].x *= sc;
                    l_p2[mi].y *= sc;
#pragma unroll
                    for (int dt = 0; dt < 4; dt++)
#pragma unroll
                        for (int j = 0; j < 4; j++) o_acc[mi][dt][j] *= sc;
                }
            }

            // ---- P = exp2(s*CSC - m), per-lane l, cvt_pk + b64 store
#pragma unroll
            for (int mi = 0; mi < 2; mi++) {
                float msc = m_s[mi];
                int q = mi * 16 + l15;
                int qx = (q & 7) << 4;
#pragma unroll
                for (int nt = 0; nt < 4; nt++) {
                    float p0 = exp2f(fmaf(s[mi][nt][0], CSC, -msc));
                    float p1 = exp2f(fmaf(s[mi][nt][1], CSC, -msc));
                    float p2 = exp2f(fmaf(s[mi][nt][2], CSC, -msc));
                    float p3 = exp2f(fmaf(s[mi][nt][3], CSC, -msc));
                    l_p2[mi].x += p0 + p2;
                    l_p2[mi].y += p1 + p3;
                    uint2 pk;
                    pk.x = f2bf2(p0, p1);
                    pk.y = f2bf2(p2, p3);
                    *(uint2*)(Pw + ((q * 128 + nt * 32 + lhi * 8) ^ qx)) = pk;
                }
            }

            // ---- PV (P wave-private; compiler orders via lgkmcnt)
            __builtin_amdgcn_s_setprio(1);
#pragma unroll
            for (int kk = 0; kk < 2; kk++) {
                bf16x8 ap[2];
#pragma unroll
                for (int mi = 0; mi < 2; mi++) {
                    int prow = mi * 16 + l15;
                    ap[mi] = *(const bf16x8*)((const char*)Pw +
                        ((prow * 128 + kk * 64 + lhi * 16) ^ ((prow & 7) << 4)));
                }
#pragma unroll
                for (int dt = 0; dt < 4; dt++) {
                    int vrow = dt * 16 + l15;
                    bf16x8 bv = *(const bf16x8*)((const char*)Vsm[cur] +
                        ((vrow * 128 + kk * 64 + lhi * 16) ^ ((vrow & 7) << 4)));
#pragma unroll
                    for (int mi = 0; mi < 2; mi++)
                        o_acc[mi][dt] = __builtin_amdgcn_mfma_f32_16x16x32_bf16(
                            ap[mi], bv, o_acc[mi][dt], 0, 0, 0);
                }
            }
            __builtin_amdgcn_s_setprio(0);
            __syncthreads();   // implicit vmcnt(0): next tile's DMA has landed
        }

        // ---- epilogue
        float l_red[2];
#pragma unroll
        for (int mi = 0; mi < 2; mi++) {
            float l = l_p2[mi].x + l_p2[mi].y;
            l += __shfl_xor(l, 16, 64);
            l += __shfl_xor(l, 32, 64);
            l_red[mi] = l;
        }
#pragma unroll
        for (int mi = 0; mi < 2; mi++)
#pragma unroll
            for (int j = 0; j < 4; j++) {
                float l = __shfl(l_red[mi], lhi * 4 + j, 64);
                float rinv = 1.f / l;
                int t = qbase + mi * 16 + lhi * 4 + j;
#pragma unroll
                for (int dt = 0; dt < 4; dt++) {
                    int cc = h * 64 + dt * 16 + l15;
                    Aout[((size_t)b * 2048 + t) * 1024 + cc] =
                        f2bf(o_acc[mi][dt][j] * rinv);
                }
            }
    }
}

// ---------------------------------------------------------------------------
extern "C" void kernel_launch(void* const* d_in, const int* in_sizes, int n_in,
                              void* d_out, int out_size, void* d_ws,
                              size_t ws_size, hipStream_t stream) {
    const float* x = (const float*)d_in[0];       // [4,2048,1024]
    const float* W_attn = (const float*)d_in[1];  // [1024,3072]
    const float* b_attn = (const float*)d_in[2];  // [3072]
    const float* W_proj = (const float*)d_in[3];  // [1024,1024]
    const float* b_proj = (const float*)d_in[4];  // [1024]
    float* out = (float*)d_out;                   // [4,2048,1024]

    char* ws = (char*)d_ws;
    const size_t MB = 1 << 20;
    unsigned short* xb  = (unsigned short*)(ws + 0);        // 16MB [8192][1024]
    unsigned short* VTb = (unsigned short*)(ws + 0);        // reuse post-GEMM1
    unsigned short* WaT = (unsigned short*)(ws + 16 * MB);  // 6MB
    unsigned short* WpT = (unsigned short*)(ws + 22 * MB);  // 2MB
    unsigned short* Qb  = (unsigned short*)(ws + 24 * MB);  // 16MB [64][2048][64]
    unsigned short* Kb  = (unsigned short*)(ws + 40 * MB);  // 16MB [64][2048][64]
    unsigned short* Vb  = (unsigned short*)(ws + 56 * MB);  // 16MB [64][2048][64]
    unsigned short* Att = (unsigned short*)(ws + 72 * MB);  // 16MB [8192][1024]
    unsigned int*   ctr = (unsigned int*)(ws + 56 * MB);    // Vb dead post-vtrans

    const int Mtok = 8192;

    cvt_f32_bf16<<<8192, 256, 0, stream>>>(x, xb, Mtok * 1024);
    transpose_to_bf16<<<96 * 32, 256, 0, stream>>>(W_attn, WaT, 3072);
    transpose_to_bf16<<<32 * 32, 256, 0, stream>>>(W_proj, WpT, 1024);

    // qkv GEMM: M=8192, N=3072, K=1024 -> Q/K/V (all row-major)
    gemm_bf16<0><<<64 * 24, 256, 0, stream>>>(xb, WaT, b_attn, nullptr, Qb, Kb,
                                              Vb, Mtok, 3072, 1024, 64);

    // V [bh][t][d] -> VT [bh][d][t]  (xb region is free now)
    vtrans<<<64 * 32, 256, 0, stream>>>(Vb, VTb);

    // work-queue counter := 0 (Vb region is dead after vtrans; stream-ordered)
    hipMemsetAsync(ctr, 0, sizeof(unsigned int), stream);

    // causal attention: persistent, 3 blocks/CU
    attn_kernel<<<768, 256, 0, stream>>>(Qb, Kb, VTb, Att, ctr);

    // proj GEMM: M=8192, N=1024, K=1024 -> fp32 out
    gemm_bf16<1><<<64 * 8, 256, 0, stream>>>(Att, WpT, b_proj, out, nullptr,
                                             nullptr, nullptr, Mtok, 1024, 1024,
                                             64);
}